// Round 13
// baseline (377.687 us; speedup 1.0000x reference)
//
#include <hip/hip_runtime.h>
#include <math.h>

typedef __bf16 bf16x8 __attribute__((ext_vector_type(8)));
typedef float f32x4 __attribute__((ext_vector_type(4)));
typedef short short8v __attribute__((ext_vector_type(8)));

#define MARGIN 0.01f
#define NCAND 32

#define WAITL   do { asm volatile("s_waitcnt lgkmcnt(0)" ::: "memory"); __builtin_amdgcn_sched_barrier(0); } while (0)
#define WAITV0  do { asm volatile("s_waitcnt vmcnt(0)" ::: "memory"); __builtin_amdgcn_sched_barrier(0); } while (0)
#define WAITV12 do { asm volatile("s_waitcnt vmcnt(12)" ::: "memory"); __builtin_amdgcn_sched_barrier(0); } while (0)
#define BARR    do { __builtin_amdgcn_s_barrier(); __builtin_amdgcn_sched_barrier(0); } while (0)

__device__ __forceinline__ unsigned short f2bf(float f) {
  unsigned u = __float_as_uint(f);
  u += 0x7fffu + ((u >> 16) & 1u);
  return (unsigned short)(u >> 16);
}
__device__ __forceinline__ float tanh_fast(float x) {
  float e = __builtin_amdgcn_exp2f(x * 2.885390081777927f);
  return 1.f - 2.f * __builtin_amdgcn_rcpf(e + 1.f);
}
__device__ __forceinline__ void gl_lds16(const void* g, void* l) {
  __builtin_amdgcn_global_load_lds(
      (const __attribute__((address_space(1))) unsigned int*)g,
      (__attribute__((address_space(3))) unsigned int*)l, 16, 0, 0);
}
// DPP row_shr 16-lane reduce; row sum lands in lane 15 (verified R11).
__device__ __forceinline__ float dpp_row_reduce(float v) {
  int x;
  x = __builtin_amdgcn_update_dpp(0, __builtin_bit_cast(int, v), 0x118, 0xf, 0xf, true);
  v += __builtin_bit_cast(float, x);
  x = __builtin_amdgcn_update_dpp(0, __builtin_bit_cast(int, v), 0x114, 0xf, 0xf, true);
  v += __builtin_bit_cast(float, x);
  x = __builtin_amdgcn_update_dpp(0, __builtin_bit_cast(int, v), 0x112, 0xf, 0xf, true);
  v += __builtin_bit_cast(float, x);
  x = __builtin_amdgcn_update_dpp(0, __builtin_bit_cast(int, v), 0x111, 0xf, 0xf, true);
  v += __builtin_bit_cast(float, x);
  return v;
}

__global__ __launch_bounds__(256) void prep_inp_k(const float* __restrict__ x,
    const float* __restrict__ Wi, const float* __restrict__ bi, float* __restrict__ inp) {
  int gid = blockIdx.x * 256 + threadIdx.x;
  int b = gid >> 9, h = gid & 511;
  const float* xr = x + b * 512;
  const float* wr = Wi + h * 512;
  float acc = bi[h];
  #pragma unroll 4
  for (int k = 0; k < 512; k += 4) {
    float4 xv = *(const float4*)(xr + k);
    float4 wv = *(const float4*)(wr + k);
    acc += xv.x * wv.x + xv.y * wv.y + xv.z * wv.z + xv.w * wv.w;
  }
  inp[gid] = acc;
}

// Packed: region (strip, KS 0..15) = 256 rows x 32 k (64B rows), row-major.
__global__ __launch_bounds__(256) void prep_w_pack_k(const float* __restrict__ w0,
    const float* __restrict__ w1, const float* __restrict__ w2, const float* __restrict__ w3,
    short* __restrict__ Whi) {
  int gid = blockIdx.x * 256 + threadIdx.x;
  if (gid >= 131072) return;
  int c = gid & 3, row = (gid >> 2) & 255, TK = gid >> 10;  // TK = TN*16+KS
  int TN = TK >> 4, KS = TK & 15;
  int n = TN * 256 + row;
  int g = n >> 9, h = n & 511;
  const float* w = (g == 0) ? w0 : (g == 1) ? w1 : (g == 2) ? w2 : w3;
  const float* src = w + (size_t)h * 512 + KS * 32 + c * 8;
  float f[8];
  *(float4*)&f[0] = *(const float4*)(src);
  *(float4*)&f[4] = *(const float4*)(src + 4);
  short8v hv;
  #pragma unroll
  for (int i = 0; i < 8; ++i) hv[i] = (short)f2bf(f[i]);
  *(short8v*)(Whi + (size_t)gid * 8) = hv;
}

__global__ __launch_bounds__(256) void prep_ctx_pack_k(const float* __restrict__ ctx,
    short* __restrict__ Chi) {
  int gid = blockIdx.x * 256 + threadIdx.x;
  int c = gid & 3, row = (gid >> 2) & 255, TK = gid >> 10;  // TK = TM*16+KS
  int TM = TK >> 4, KS = TK & 15;
  size_t m = (size_t)TM * 256 + row;
  int k = KS * 32 + c * 8;
  float f[8];
  *(float4*)&f[0] = *(const float4*)(ctx + m * 512 + k);
  *(float4*)&f[4] = *(const float4*)(ctx + m * 512 + k + 4);
  short8v hv;
  #pragma unroll
  for (int i = 0; i < 8; ++i) hv[i] = (short)f2bf(f[i]);
  *(short8v*)(Chi + (size_t)gid * 8) = hv;
}

#define LOADF(A_, B_, TT) do { \
    const short* pa = Chi + aRegBase + (size_t)(TT) * 8192 + aoff; \
    const short* pb = Whi + bRegBase + (size_t)(TT) * 8192 + boff; \
    _Pragma("unroll") \
    for (int mi = 0; mi < 8; ++mi) A_[mi] = *(const bf16x8*)(pa + mi * 512); \
    _Pragma("unroll") \
    for (int ni = 0; ni < 4; ++ni) B_[ni] = *(const bf16x8*)(pb + ni * 512); \
  } while (0)

#define MFMA_SET(A_, B_) do { \
    __builtin_amdgcn_s_setprio(1); \
    _Pragma("unroll") \
    for (int mi = 0; mi < 8; ++mi) { \
      acc[mi][0] = __builtin_amdgcn_mfma_f32_16x16x32_bf16(A_[mi], B_[0], acc[mi][0], 0, 0, 0); \
      acc[mi][1] = __builtin_amdgcn_mfma_f32_16x16x32_bf16(A_[mi], B_[1], acc[mi][1], 0, 0, 0); \
      acc[mi][2] = __builtin_amdgcn_mfma_f32_16x16x32_bf16(A_[mi], B_[2], acc[mi][2], 0, 0, 0); \
      acc[mi][3] = __builtin_amdgcn_mfma_f32_16x16x32_bf16(A_[mi], B_[3], acc[mi][3], 0, 0, 0); \
    } \
    __builtin_amdgcn_s_setprio(0); \
    __builtin_amdgcn_sched_barrier(0); \
  } while (0)

// Barrier-free direct-L2 GEMM: 256x256 tile, 16 K-tiles BK=32, 8 waves (2x4),
// per-wave 128x64. Fragments loaded straight from packed global (each frag
// read = dense coalesced 1KB), ping-pong reg double-buffer, counted vmcnt(12).
// NO LDS staging, NO barriers in the K-loop: waves are private pipelines.
__global__ __launch_bounds__(512, 2) void gemm_direct_k(
    const short* __restrict__ Chi, const short* __restrict__ Whi,
    const float* __restrict__ inp,
    const float* __restrict__ bc0, const float* __restrict__ bc1,
    const float* __restrict__ bc2, const float* __restrict__ bc3,
    const float* __restrict__ V, float* __restrict__ att) {
  __shared__ float sV[256], sPre[256];

  const int t = threadIdx.x;
  int d = blockIdx.x + (blockIdx.y << 3);
  int work = (d & 7) * 256 + (d >> 3);           // XCD-contiguous chunks
  int mt = work >> 3, nt = work & 7;
  int b = mt >> 3;
  int g = nt >> 1, h0 = (nt & 1) * 256;

  if (t < 256) {
    const float* bc = (g == 0) ? bc0 : (g == 1) ? bc1 : (g == 2) ? bc2 : bc3;
    sV[t] = V[h0 + t];
    sPre[t] = inp[b * 512 + h0 + t] + bc[h0 + t];
  }
  __syncthreads();

  const int lane = t & 63, wid = t >> 6;
  const int wr = wid >> 2, wc = wid & 3;
  const int fr = lane & 15, fq = lane >> 4;
  const size_t aRegBase = (size_t)(mt * 16) * 8192;
  const size_t bRegBase = (size_t)(nt * 16) * 8192;
  const int aoff = (wr * 128 + fr) * 32 + fq * 8;
  const int boff = (wc * 64 + fr) * 32 + fq * 8;

  f32x4 acc[8][4];
  #pragma unroll
  for (int i = 0; i < 8; ++i)
    #pragma unroll
    for (int j = 0; j < 4; ++j) acc[i][j] = (f32x4){0.f, 0.f, 0.f, 0.f};

  bf16x8 a0[8], b0v[4], a1[8], b1v[4];
  LOADF(a0, b0v, 0);
  #pragma unroll
  for (int it = 0; it < 8; ++it) {
    LOADF(a1, b1v, 2 * it + 1);        // issue 12 loads (tile t1)
    WAITV12;                           // tile t0's 12 loads done
    MFMA_SET(a0, b0v);                 // consume t0 (covers t1's latency)
    if (it < 7) {
      LOADF(a0, b0v, 2 * it + 2);      // issue 12 loads (tile t0')
      WAITV12;                         // t1 ready
    } else {
      WAITV0;
    }
    MFMA_SET(a1, b1v);                 // consume t1
  }

  // epilogue: att[b, g*2048 + s] += sum_n V[h]*tanh(pre[h] + Y[n,s])
  float vV[4], vP[4];
  #pragma unroll
  for (int ni = 0; ni < 4; ++ni) {
    int j = wc * 64 + ni * 16 + fr;
    vV[ni] = sV[j];
    vP[ni] = sPre[j];
  }
  size_t abatt = (size_t)b * 8192 + (size_t)g * 2048;
  #pragma unroll
  for (int mi = 0; mi < 8; ++mi) {
    #pragma unroll
    for (int r = 0; r < 4; ++r) {
      float sum = 0.f;
      #pragma unroll
      for (int ni = 0; ni < 4; ++ni)
        sum += vV[ni] * tanh_fast(vP[ni] + acc[mi][ni][r]);
      sum = dpp_row_reduce(sum);
      if (fr == 15) {
        int s = (mt * 256 + wr * 128 + mi * 16 + fq * 4 + r) & 2047;
        atomicAdd(&att[abatt + s], sum);
      }
    }
  }
}

// Fallback (no presplit workspace): R11's LDS-staged kernel, fp32->bf16 inline.
__global__ __launch_bounds__(512, 2) void gemm_fallback_k(
    const float* __restrict__ ctx, const short* __restrict__ Whi,
    const float* __restrict__ inp,
    const float* __restrict__ bc0, const float* __restrict__ bc1,
    const float* __restrict__ bc2, const float* __restrict__ bc3,
    const float* __restrict__ V, float* __restrict__ att) {
  __shared__ __align__(16) short smem[2][2][8192];
  __shared__ float sV[256], sPre[256];
  const int t = threadIdx.x;
  int d = blockIdx.x + (blockIdx.y << 3);
  int work = (d & 7) * 256 + (d >> 3);
  int mt = work >> 3, nt = work & 7;
  int b = mt >> 3;
  int g = nt >> 1, h0 = (nt & 1) * 256;
  if (t < 256) {
    const float* bc = (g == 0) ? bc0 : (g == 1) ? bc1 : (g == 2) ? bc2 : bc3;
    sV[t] = V[h0 + t];
    sPre[t] = inp[b * 512 + h0 + t] + bc[h0 + t];
  }
  const int toff = t * 8;
  auto stageA_reg = [&](int tile) {
    #pragma unroll
    for (int pass = 0; pass < 2; ++pass) {
      int cc = pass * 512 + t;
      int c = cc & 3, r = cc >> 2;
      int k = tile * 32 + c * 8;
      const float* src = ctx + ((size_t)mt * 256 + r) * 512 + k;
      float f[8];
      *(float4*)&f[0] = *(const float4*)src;
      *(float4*)&f[4] = *(const float4*)(src + 4);
      short8v hv;
      #pragma unroll
      for (int i = 0; i < 8; ++i) hv[i] = (short)f2bf(f[i]);
      *(short8v*)(&smem[tile & 1][0][r * 32 + c * 8]) = hv;
    }
  };
  auto stageB = [&](int tile) {
    const short* gB = Whi + (((size_t)nt * 16 + tile) << 13) + toff;
    short* lB = &smem[tile & 1][1][0];
    gl_lds16(gB,        lB + toff);
    gl_lds16(gB + 4096, lB + toff + 4096);
  };
  f32x4 acc[8][4];
  #pragma unroll
  for (int i = 0; i < 8; ++i)
    #pragma unroll
    for (int j = 0; j < 4; ++j) acc[i][j] = (f32x4){0.f, 0.f, 0.f, 0.f};
  const int lane = t & 63, wid = t >> 6;
  const int wr = wid >> 2, wc = wid & 3;
  const int fr = lane & 15, fq = lane >> 4;
  const int abase = (wr * 128 + fr) * 32 + fq * 8;
  const int bbase = (wc * 64 + fr) * 32 + fq * 8;
  stageA_reg(0); stageB(0);
  WAITV0; WAITL;
  BARR;
  for (int tt = 0; tt < 16; ++tt) {
    const short* sa = &smem[tt & 1][0][0];
    const short* sb = &smem[tt & 1][1][0];
    bf16x8 a[8], bfr[4];
    #pragma unroll
    for (int mi = 0; mi < 8; ++mi)
      a[mi] = *(const bf16x8*)(sa + abase + mi * 512);
    bfr[0] = *(const bf16x8*)(sb + bbase);
    bfr[1] = *(const bf16x8*)(sb + bbase + 512);
    bfr[2] = *(const bf16x8*)(sb + bbase + 1024);
    bfr[3] = *(const bf16x8*)(sb + bbase + 1536);
    WAITL;
    MFMA_SET(a, bfr);
    if (tt < 15) { stageA_reg(tt + 1); stageB(tt + 1); WAITV0; WAITL; }
    BARR;
  }
  float vV[4], vP[4];
  #pragma unroll
  for (int ni = 0; ni < 4; ++ni) {
    int j = wc * 64 + ni * 16 + fr;
    vV[ni] = sV[j];
    vP[ni] = sPre[j];
  }
  size_t abatt = (size_t)b * 8192 + (size_t)g * 2048;
  #pragma unroll
  for (int mi = 0; mi < 8; ++mi) {
    #pragma unroll
    for (int r = 0; r < 4; ++r) {
      float sum = 0.f;
      #pragma unroll
      for (int ni = 0; ni < 4; ++ni)
        sum += vV[ni] * tanh_fast(vP[ni] + acc[mi][ni][r]);
      sum = dpp_row_reduce(sum);
      if (fr == 15) {
        int s = (mt * 256 + wr * 128 + mi * 16 + fq * 4 + r) & 2047;
        atomicAdd(&att[abatt + s], sum);
      }
    }
  }
}

// Fused tail: max + denom + candidates, exact fp32 rescore, final outputs.
__global__ __launch_bounds__(256) void tail_k(const float* __restrict__ att,
    const unsigned char* __restrict__ mask, const float* __restrict__ ctx,
    const float* __restrict__ Wc0, const float* __restrict__ Wc1,
    const float* __restrict__ Wc2, const float* __restrict__ Wc3,
    const float* __restrict__ bc0, const float* __restrict__ bc1,
    const float* __restrict__ bc2, const float* __restrict__ bc3,
    const float* __restrict__ inp, const float* __restrict__ V,
    float* __restrict__ out) {
  int b = blockIdx.x, t = threadIdx.x;
  __shared__ float sred[256];
  __shared__ float sctx[512];
  __shared__ int scnt;
  __shared__ int scand_j[NCAND];
  __shared__ float scand_a[NCAND];
  __shared__ float sexact[NCAND];

  if (t == 0) scnt = 0;
  float bm = -1e30f;
  for (int j = t; j < 8192; j += 256) {
    if (mask[b * 2048 + (j & 2047)]) continue;
    bm = fmaxf(bm, att[(size_t)b * 8192 + j]);
  }
  sred[t] = bm;
  __syncthreads();
  for (int s2 = 128; s2 > 0; s2 >>= 1) {
    if (t < s2) sred[t] = fmaxf(sred[t], sred[t + s2]);
    __syncthreads();
  }
  float mx = sred[0];
  float Lref = 10.f * tanhf(mx);
  __syncthreads();
  float se = 0.f;
  for (int j = t; j < 8192; j += 256) {
    if (mask[b * 2048 + (j & 2047)]) continue;
    float a = att[(size_t)b * 8192 + j];
    se += expf(10.f * tanhf(a) - Lref);
    if (a >= mx - MARGIN) {
      int slot = atomicAdd(&scnt, 1);
      if (slot < NCAND) { scand_j[slot] = j; scand_a[slot] = a; }
    }
  }
  sred[t] = se;
  __syncthreads();
  for (int s2 = 128; s2 > 0; s2 >>= 1) {
    if (t < s2) sred[t] += sred[t + s2];
    __syncthreads();
  }
  float den = sred[0];
  int n = min(scnt, NCAND);
  for (int j = t; j < 2048; j += 256)
    out[64 + b * 2048 + j] = mask[b * 2048 + j] ? 1.0f : 0.0f;
  for (int i = 0; i < n; ++i) {
    int jj = scand_j[i];
    int g = jj >> 11, s = jj & 2047;
    const float* W  = (g == 0) ? Wc0 : (g == 1) ? Wc1 : (g == 2) ? Wc2 : Wc3;
    const float* bc = (g == 0) ? bc0 : (g == 1) ? bc1 : (g == 2) ? bc2 : bc3;
    const float* cr = ctx + ((size_t)b * 2048 + s) * 512;
    __syncthreads();
    sctx[t] = cr[t];
    sctx[t + 256] = cr[t + 256];
    __syncthreads();
    float total = 0.f;
    #pragma unroll
    for (int hh = 0; hh < 2; ++hh) {
      int h = t + hh * 256;
      const float* wrp = W + (size_t)h * 512;
      float acc = 0.f;
      #pragma unroll 4
      for (int k = 0; k < 512; k += 4) {
        float4 wv = *(const float4*)(wrp + k);
        acc += wv.x * sctx[k] + wv.y * sctx[k + 1] + wv.z * sctx[k + 2] + wv.w * sctx[k + 3];
      }
      total += V[h] * tanhf(inp[b * 512 + h] + bc[h] + acc);
    }
    sred[t] = total;
    __syncthreads();
    for (int s2 = 128; s2 > 0; s2 >>= 1) {
      if (t < s2) sred[t] += sred[t + s2];
      __syncthreads();
    }
    if (t == 0) sexact[i] = sred[0];
  }
  __syncthreads();
  if (t == 0) {
    float dd = den, best = -1e30f;
    int bj = 0x7fffffff;
    for (int i = 0; i < n; ++i) {
      float e = sexact[i];
      int j = scand_j[i];
      dd += expf(10.f * tanhf(e) - Lref) - expf(10.f * tanhf(scand_a[i]) - Lref);
      if (e > best || (e == best && j < bj)) { best = e; bj = j; }
    }
    out[b] = (float)bj;
    out[32 + b] = expf(10.f * tanhf(best) - Lref) / dd;
  }
}

extern "C" void kernel_launch(void* const* d_in, const int* in_sizes, int n_in,
                              void* d_out, int out_size, void* d_ws, size_t ws_size,
                              hipStream_t stream) {
  const float* x    = (const float*)d_in[0];
  const float* ctx  = (const float*)d_in[1];
  const unsigned char* mask = (const unsigned char*)d_in[2];
  const float* Wi   = (const float*)d_in[3];
  const float* bi   = (const float*)d_in[4];
  const float* Wc0  = (const float*)d_in[5];
  const float* bc0  = (const float*)d_in[6];
  const float* Wc1  = (const float*)d_in[7];
  const float* bc1  = (const float*)d_in[8];
  const float* Wc2  = (const float*)d_in[9];
  const float* bc2  = (const float*)d_in[10];
  const float* Wc3  = (const float*)d_in[11];
  const float* bc3  = (const float*)d_in[12];
  const float* V    = (const float*)d_in[13];
  float* out = (float*)d_out;

  float* inp    = (float*)d_ws;            // 16384 f32
  float* att    = inp + 16384;             // 262144 f32
  short* Whi    = (short*)(att + 262144);  // 1048576 shorts
  short* Chi    = Whi + 1048576;           // 33554432 shorts
  size_t need = (size_t)((char*)(Chi + 33554432) - (char*)d_ws);
  bool presplit = ws_size >= need;

  hipMemsetAsync(att, 0, 262144 * sizeof(float), stream);
  prep_inp_k<<<64, 256, 0, stream>>>(x, Wi, bi, inp);
  prep_w_pack_k<<<512, 256, 0, stream>>>(Wc0, Wc1, Wc2, Wc3, Whi);
  if (presplit) {
    prep_ctx_pack_k<<<16384, 256, 0, stream>>>(ctx, Chi);
    gemm_direct_k<<<dim3(8, 256), 512, 0, stream>>>(Chi, Whi,
        inp, bc0, bc1, bc2, bc3, V, att);
  } else {
    gemm_fallback_k<<<dim3(8, 256), 512, 0, stream>>>(ctx, Whi,
        inp, bc0, bc1, bc2, bc3, V, att);
  }
  tail_k<<<32, 256, 0, stream>>>(att, mask, ctx, Wc0, Wc1, Wc2, Wc3,
      bc0, bc1, bc2, bc3, inp, V, out);
}

// Round 14
// 311.956 us; speedup vs baseline: 1.2107x; 1.2107x over previous
//
#include <hip/hip_runtime.h>
#include <math.h>

typedef __bf16 bf16x8 __attribute__((ext_vector_type(8)));
typedef float f32x4 __attribute__((ext_vector_type(4)));
typedef short short8v __attribute__((ext_vector_type(8)));

#define MARGIN 0.01f
#define NCAND 32

#define WAITL  do { asm volatile("s_waitcnt lgkmcnt(0)" ::: "memory"); __builtin_amdgcn_sched_barrier(0); } while (0)
#define WAITV0 do { asm volatile("s_waitcnt vmcnt(0)" ::: "memory"); __builtin_amdgcn_sched_barrier(0); } while (0)
#define WAITV4 do { asm volatile("s_waitcnt vmcnt(4)" ::: "memory"); __builtin_amdgcn_sched_barrier(0); } while (0)
#define WAITV8 do { asm volatile("s_waitcnt vmcnt(8)" ::: "memory"); __builtin_amdgcn_sched_barrier(0); } while (0)
#define BARR   do { __builtin_amdgcn_s_barrier(); __builtin_amdgcn_sched_barrier(0); } while (0)

__device__ __forceinline__ unsigned short f2bf(float f) {
  unsigned u = __float_as_uint(f);
  u += 0x7fffu + ((u >> 16) & 1u);
  return (unsigned short)(u >> 16);
}
__device__ __forceinline__ float tanh_fast(float x) {
  float e = __builtin_amdgcn_exp2f(x * 2.885390081777927f);
  return 1.f - 2.f * __builtin_amdgcn_rcpf(e + 1.f);
}
__device__ __forceinline__ void gl_lds16(const void* g, void* l) {
  __builtin_amdgcn_global_load_lds(
      (const __attribute__((address_space(1))) unsigned int*)g,
      (__attribute__((address_space(3))) unsigned int*)l, 16, 0, 0);
}
// DPP row_shr 16-lane reduce; row sum lands in lane 15 (verified R11).
__device__ __forceinline__ float dpp_row_reduce(float v) {
  int x;
  x = __builtin_amdgcn_update_dpp(0, __builtin_bit_cast(int, v), 0x118, 0xf, 0xf, true);
  v += __builtin_bit_cast(float, x);
  x = __builtin_amdgcn_update_dpp(0, __builtin_bit_cast(int, v), 0x114, 0xf, 0xf, true);
  v += __builtin_bit_cast(float, x);
  x = __builtin_amdgcn_update_dpp(0, __builtin_bit_cast(int, v), 0x112, 0xf, 0xf, true);
  v += __builtin_bit_cast(float, x);
  x = __builtin_amdgcn_update_dpp(0, __builtin_bit_cast(int, v), 0x111, 0xf, 0xf, true);
  v += __builtin_bit_cast(float, x);
  return v;
}

// ---- fused prep: blocks [0,16384) ctx-pack, [16384,16896) W-pack, rest inp ----
__global__ __launch_bounds__(256) void prep_all_k(
    const float* __restrict__ ctx, const float* __restrict__ x,
    const float* __restrict__ Wi, const float* __restrict__ bi,
    const float* __restrict__ w0, const float* __restrict__ w1,
    const float* __restrict__ w2, const float* __restrict__ w3,
    short* __restrict__ Chi, short* __restrict__ Whi, float* __restrict__ inp) {
  int bid = blockIdx.x;
  if (bid < 16384) {
    int gid = bid * 256 + threadIdx.x;   // 4194304 chunks of 8
    int c = gid & 3, row = (gid >> 2) & 255, TK = gid >> 10;  // TK = TM*16+KS
    int TM = TK >> 4, KS = TK & 15;
    size_t m = (size_t)TM * 256 + row;
    int k = KS * 32 + c * 8;
    float f[8];
    *(float4*)&f[0] = *(const float4*)(ctx + m * 512 + k);
    *(float4*)&f[4] = *(const float4*)(ctx + m * 512 + k + 4);
    short8v hv;
    #pragma unroll
    for (int i = 0; i < 8; ++i) hv[i] = (short)f2bf(f[i]);
    *(short8v*)(Chi + (size_t)gid * 8) = hv;
  } else if (bid < 16896) {
    int gid = (bid - 16384) * 256 + threadIdx.x;
    if (gid < 131072) {
      int c = gid & 3, row = (gid >> 2) & 255, TK = gid >> 10;  // TK = TN*16+KS
      int TN = TK >> 4, KS = TK & 15;
      int n = TN * 256 + row;
      int g = n >> 9, h = n & 511;
      const float* w = (g == 0) ? w0 : (g == 1) ? w1 : (g == 2) ? w2 : w3;
      const float* src = w + (size_t)h * 512 + KS * 32 + c * 8;
      float f[8];
      *(float4*)&f[0] = *(const float4*)(src);
      *(float4*)&f[4] = *(const float4*)(src + 4);
      short8v hv;
      #pragma unroll
      for (int i = 0; i < 8; ++i) hv[i] = (short)f2bf(f[i]);
      *(short8v*)(Whi + (size_t)gid * 8) = hv;
    }
  } else {
    int gid = (bid - 16896) * 256 + threadIdx.x;   // 16384
    int b = gid >> 9, h = gid & 511;
    const float* xr = x + b * 512;
    const float* wr = Wi + h * 512;
    float acc = bi[h];
    #pragma unroll 4
    for (int k = 0; k < 512; k += 4) {
      float4 xv = *(const float4*)(xr + k);
      float4 wv = *(const float4*)(wr + k);
      acc += xv.x * wv.x + xv.y * wv.y + xv.z * wv.z + xv.w * wv.w;
    }
    inp[gid] = acc;
  }
}

// ---- standalone preps for the fallback path ----
__global__ __launch_bounds__(256) void prep_inp_k(const float* __restrict__ x,
    const float* __restrict__ Wi, const float* __restrict__ bi, float* __restrict__ inp) {
  int gid = blockIdx.x * 256 + threadIdx.x;
  int b = gid >> 9, h = gid & 511;
  const float* xr = x + b * 512;
  const float* wr = Wi + h * 512;
  float acc = bi[h];
  #pragma unroll 4
  for (int k = 0; k < 512; k += 4) {
    float4 xv = *(const float4*)(xr + k);
    float4 wv = *(const float4*)(wr + k);
    acc += xv.x * wv.x + xv.y * wv.y + xv.z * wv.z + xv.w * wv.w;
  }
  inp[gid] = acc;
}
__global__ __launch_bounds__(256) void prep_w_pack_k(const float* __restrict__ w0,
    const float* __restrict__ w1, const float* __restrict__ w2, const float* __restrict__ w3,
    short* __restrict__ Whi) {
  int gid = blockIdx.x * 256 + threadIdx.x;
  if (gid >= 131072) return;
  int c = gid & 3, row = (gid >> 2) & 255, TK = gid >> 10;
  int TN = TK >> 4, KS = TK & 15;
  int n = TN * 256 + row;
  int g = n >> 9, h = n & 511;
  const float* w = (g == 0) ? w0 : (g == 1) ? w1 : (g == 2) ? w2 : w3;
  const float* src = w + (size_t)h * 512 + KS * 32 + c * 8;
  float f[8];
  *(float4*)&f[0] = *(const float4*)(src);
  *(float4*)&f[4] = *(const float4*)(src + 4);
  short8v hv;
  #pragma unroll
  for (int i = 0; i < 8; ++i) hv[i] = (short)f2bf(f[i]);
  *(short8v*)(Whi + (size_t)gid * 8) = hv;
}

// ---- R11 gemm (measured 184 us): 256x256 tile, 16 K-tiles BK=32, 8 waves,
// 4-deep LDS ring, counted vmcnt(8), ONE barrier per K-tile. ----
template<bool PRESPLIT>
__global__ __launch_bounds__(512, 2) void gemm_att_k(
    const float* __restrict__ ctx, const short* __restrict__ Chi,
    const short* __restrict__ Whi,
    const float* __restrict__ inp,
    const float* __restrict__ bc0, const float* __restrict__ bc1,
    const float* __restrict__ bc2, const float* __restrict__ bc3,
    const float* __restrict__ V, float* __restrict__ att) {
  __shared__ __align__(16) short smem[4][2][8192];   // 128 KiB: [ring][A|B]
  __shared__ float sV[256], sPre[256];

  const int t = threadIdx.x;
  int d = blockIdx.x + (blockIdx.y << 3);
  int work = (d & 7) * 256 + (d >> 3);           // XCD-contiguous chunks
  int mt = work >> 3, nt = work & 7;
  int b = mt >> 3;
  int g = nt >> 1, h0 = (nt & 1) * 256;

  if (t < 256) {
    const float* bc = (g == 0) ? bc0 : (g == 1) ? bc1 : (g == 2) ? bc2 : bc3;
    sV[t] = V[h0 + t];
    sPre[t] = inp[b * 512 + h0 + t] + bc[h0 + t];
  }

  const int toff = t * 8;
  auto stageA = [&](int tile) {
    const short* gA = Chi + (((size_t)mt * 16 + tile) << 13) + toff;
    short* lA = &smem[tile & 3][0][0];
    gl_lds16(gA,        lA + toff);
    gl_lds16(gA + 4096, lA + toff + 4096);
  };
  auto stageB = [&](int tile) {
    const short* gB = Whi + (((size_t)nt * 16 + tile) << 13) + toff;
    short* lB = &smem[tile & 3][1][0];
    gl_lds16(gB,        lB + toff);
    gl_lds16(gB + 4096, lB + toff + 4096);
  };
  auto stageA_reg = [&](int tile) {
    #pragma unroll
    for (int pass = 0; pass < 2; ++pass) {
      int cc = pass * 512 + t;
      int c = cc & 3, r = cc >> 2;
      int k = tile * 32 + c * 8;
      const float* src = ctx + ((size_t)mt * 256 + r) * 512 + k;
      float f[8];
      *(float4*)&f[0] = *(const float4*)src;
      *(float4*)&f[4] = *(const float4*)(src + 4);
      short8v hv;
      #pragma unroll
      for (int i = 0; i < 8; ++i) hv[i] = (short)f2bf(f[i]);
      *(short8v*)(&smem[tile & 3][0][r * 32 + c * 8]) = hv;
    }
  };

  f32x4 acc[8][4];
  #pragma unroll
  for (int i = 0; i < 8; ++i)
    #pragma unroll
    for (int j = 0; j < 4; ++j) acc[i][j] = (f32x4){0.f, 0.f, 0.f, 0.f};

  const int lane = t & 63, wid = t >> 6;
  const int wr = wid >> 2, wc = wid & 3;
  const int fr = lane & 15, fq = lane >> 4;
  const int abase = (wr * 128 + fr) * 32 + fq * 8;
  const int bbase = (wc * 64 + fr) * 32 + fq * 8;

  if constexpr (PRESPLIT) {
    stageA(0); stageB(0); stageA(1); stageB(1); stageA(2); stageB(2);
    WAITV8;
  } else {
    stageA_reg(0); stageB(0);
    WAITV0; WAITL;
  }
  BARR;

  #pragma unroll 4
  for (int tt = 0; tt < 16; ++tt) {
    const short* sa = &smem[tt & 3][0][0];
    const short* sb = &smem[tt & 3][1][0];
    bf16x8 a[8], b0, b1, b2, b3;
    #pragma unroll
    for (int mi = 0; mi < 8; ++mi)
      a[mi] = *(const bf16x8*)(sa + abase + mi * 512);
    b0 = *(const bf16x8*)(sb + bbase);
    b1 = *(const bf16x8*)(sb + bbase + 512);
    b2 = *(const bf16x8*)(sb + bbase + 1024);
    b3 = *(const bf16x8*)(sb + bbase + 1536);
    WAITL;
    __builtin_amdgcn_s_setprio(1);
    #pragma unroll
    for (int mi = 0; mi < 8; ++mi) {
      acc[mi][0] = __builtin_amdgcn_mfma_f32_16x16x32_bf16(a[mi], b0, acc[mi][0], 0, 0, 0);
      acc[mi][1] = __builtin_amdgcn_mfma_f32_16x16x32_bf16(a[mi], b1, acc[mi][1], 0, 0, 0);
    }
    #pragma unroll
    for (int mi = 0; mi < 8; ++mi) {
      acc[mi][2] = __builtin_amdgcn_mfma_f32_16x16x32_bf16(a[mi], b2, acc[mi][2], 0, 0, 0);
      acc[mi][3] = __builtin_amdgcn_mfma_f32_16x16x32_bf16(a[mi], b3, acc[mi][3], 0, 0, 0);
    }
    __builtin_amdgcn_s_setprio(0);
    __builtin_amdgcn_sched_barrier(0);
    if constexpr (PRESPLIT) {
      if (tt <= 12) { stageA(tt + 3); stageB(tt + 3); }
      if (tt <= 12)      { WAITV8; }
      else if (tt == 13) { WAITV4; }
      else if (tt == 14) { WAITV0; }
    } else {
      if (tt < 15) { stageA_reg(tt + 1); stageB(tt + 1); WAITV0; WAITL; }
    }
    BARR;
  }

  float vV[4], vP[4];
  #pragma unroll
  for (int ni = 0; ni < 4; ++ni) {
    int j = wc * 64 + ni * 16 + fr;
    vV[ni] = sV[j];
    vP[ni] = sPre[j];
  }
  size_t abatt = (size_t)b * 8192 + (size_t)g * 2048;
  #pragma unroll
  for (int mi = 0; mi < 8; ++mi) {
    #pragma unroll
    for (int r = 0; r < 4; ++r) {
      float sum = 0.f;
      #pragma unroll
      for (int ni = 0; ni < 4; ++ni)
        sum += vV[ni] * tanh_fast(vP[ni] + acc[mi][ni][r]);
      sum = dpp_row_reduce(sum);
      if (fr == 15) {
        int s = (mt * 256 + wr * 128 + mi * 16 + fq * 4 + r) & 2047;
        atomicAdd(&att[abatt + s], sum);
      }
    }
  }
}

// ---- tail: 1024 threads/block (4x parallelism vs R11) ----
__global__ __launch_bounds__(1024) void tail_k(const float* __restrict__ att,
    const unsigned char* __restrict__ mask, const float* __restrict__ ctx,
    const float* __restrict__ Wc0, const float* __restrict__ Wc1,
    const float* __restrict__ Wc2, const float* __restrict__ Wc3,
    const float* __restrict__ bc0, const float* __restrict__ bc1,
    const float* __restrict__ bc2, const float* __restrict__ bc3,
    const float* __restrict__ inp, const float* __restrict__ V,
    float* __restrict__ out) {
  int b = blockIdx.x, t = threadIdx.x;
  __shared__ float sred[1024];
  __shared__ float sctx[512];
  __shared__ int scnt;
  __shared__ int scand_j[NCAND];
  __shared__ float scand_a[NCAND];
  __shared__ float sexact[NCAND];

  if (t == 0) scnt = 0;
  float bm = -1e30f;
  for (int j = t; j < 8192; j += 1024) {
    if (mask[b * 2048 + (j & 2047)]) continue;
    bm = fmaxf(bm, att[(size_t)b * 8192 + j]);
  }
  sred[t] = bm;
  __syncthreads();
  for (int s2 = 512; s2 > 0; s2 >>= 1) {
    if (t < s2) sred[t] = fmaxf(sred[t], sred[t + s2]);
    __syncthreads();
  }
  float mx = sred[0];
  float Lref = 10.f * tanhf(mx);
  __syncthreads();
  float se = 0.f;
  for (int j = t; j < 8192; j += 1024) {
    if (mask[b * 2048 + (j & 2047)]) continue;
    float a = att[(size_t)b * 8192 + j];
    se += expf(10.f * tanhf(a) - Lref);
    if (a >= mx - MARGIN) {
      int slot = atomicAdd(&scnt, 1);
      if (slot < NCAND) { scand_j[slot] = j; scand_a[slot] = a; }
    }
  }
  sred[t] = se;
  __syncthreads();
  for (int s2 = 512; s2 > 0; s2 >>= 1) {
    if (t < s2) sred[t] += sred[t + s2];
    __syncthreads();
  }
  float den = sred[0];
  int n = min(scnt, NCAND);
  for (int j = t; j < 2048; j += 1024)
    out[64 + b * 2048 + j] = mask[b * 2048 + j] ? 1.0f : 0.0f;
  for (int i = 0; i < n; ++i) {
    int jj = scand_j[i];
    int g = jj >> 11, s = jj & 2047;
    const float* W  = (g == 0) ? Wc0 : (g == 1) ? Wc1 : (g == 2) ? Wc2 : Wc3;
    const float* bc = (g == 0) ? bc0 : (g == 1) ? bc1 : (g == 2) ? bc2 : bc3;
    const float* cr = ctx + ((size_t)b * 2048 + s) * 512;
    __syncthreads();
    if (t < 512) sctx[t] = cr[t];
    __syncthreads();
    float total = 0.f;
    if (t < 512) {
      const float* wrp = W + (size_t)t * 512;
      float acc = 0.f;
      #pragma unroll 4
      for (int k = 0; k < 512; k += 4) {
        float4 wv = *(const float4*)(wrp + k);
        acc += wv.x * sctx[k] + wv.y * sctx[k + 1] + wv.z * sctx[k + 2] + wv.w * sctx[k + 3];
      }
      total = V[t] * tanhf(inp[b * 512 + t] + bc[t] + acc);
    }
    sred[t] = total;
    __syncthreads();
    for (int s2 = 512; s2 > 0; s2 >>= 1) {
      if (t < s2) sred[t] += sred[t + s2];
      __syncthreads();
    }
    if (t == 0) sexact[i] = sred[0];
  }
  __syncthreads();
  if (t == 0) {
    float dd = den, best = -1e30f;
    int bj = 0x7fffffff;
    for (int i = 0; i < n; ++i) {
      float e = sexact[i];
      int j = scand_j[i];
      dd += expf(10.f * tanhf(e) - Lref) - expf(10.f * tanhf(scand_a[i]) - Lref);
      if (e > best || (e == best && j < bj)) { best = e; bj = j; }
    }
    out[b] = (float)bj;
    out[32 + b] = expf(10.f * tanhf(best) - Lref) / dd;
  }
}

extern "C" void kernel_launch(void* const* d_in, const int* in_sizes, int n_in,
                              void* d_out, int out_size, void* d_ws, size_t ws_size,
                              hipStream_t stream) {
  const float* x    = (const float*)d_in[0];
  const float* ctx  = (const float*)d_in[1];
  const unsigned char* mask = (const unsigned char*)d_in[2];
  const float* Wi   = (const float*)d_in[3];
  const float* bi   = (const float*)d_in[4];
  const float* Wc0  = (const float*)d_in[5];
  const float* bc0  = (const float*)d_in[6];
  const float* Wc1  = (const float*)d_in[7];
  const float* bc1  = (const float*)d_in[8];
  const float* Wc2  = (const float*)d_in[9];
  const float* bc2  = (const float*)d_in[10];
  const float* Wc3  = (const float*)d_in[11];
  const float* bc3  = (const float*)d_in[12];
  const float* V    = (const float*)d_in[13];
  float* out = (float*)d_out;

  float* inp    = (float*)d_ws;            // 16384 f32
  float* att    = inp + 16384;             // 262144 f32
  short* Whi    = (short*)(att + 262144);  // 1048576 shorts
  short* Chi    = Whi + 1048576;           // 33554432 shorts
  size_t need = (size_t)((char*)(Chi + 33554432) - (char*)d_ws);
  bool presplit = ws_size >= need;

  hipMemsetAsync(att, 0, 262144 * sizeof(float), stream);
  if (presplit) {
    prep_all_k<<<16960, 256, 0, stream>>>(ctx, x, Wi, bi,
        Wc0, Wc1, Wc2, Wc3, Chi, Whi, inp);
    gemm_att_k<true><<<dim3(8, 256), 512, 0, stream>>>(ctx, Chi, Whi,
        inp, bc0, bc1, bc2, bc3, V, att);
  } else {
    prep_inp_k<<<64, 256, 0, stream>>>(x, Wi, bi, inp);
    prep_w_pack_k<<<512, 256, 0, stream>>>(Wc0, Wc1, Wc2, Wc3, Whi);
    gemm_att_k<false><<<dim3(8, 256), 512, 0, stream>>>(ctx, nullptr, Whi,
        inp, bc0, bc1, bc2, bc3, V, att);
  }
  tail_k<<<32, 1024, 0, stream>>>(att, mask, ctx, Wc0, Wc1, Wc2, Wc3,
      bc0, bc1, bc2, bc3, inp, V, out);
}